// Round 7
// baseline (131.015 us; speedup 1.0000x reference)
//
#include <hip/hip_runtime.h>
#include <math.h>

// EdgeAwareLoss — round 10: champion (r3, 44.8us) + finalize folded into
// edge_loss via last-block reduction (r7/r8-validated pattern).
//
// Session ledger: r3=44.8 (3-kernel nibble-SWAR champion), every structural
// rewrite since (fused streams r4, bit-sliced r5, stream/stencil split r6,
// row bands r7/r8, wave-autonomous r9) landed 45-68us. The system's floor
// couples 128MB traffic (~20us) with ~10-15us stencil VALU through phase
// structures; the champion's 64x64-tile pipeline is the best measured
// overlap. r10 keeps it verbatim and removes one dispatch boundary: the
// 1-block finalize becomes a last-block epilogue (threadfence + atomic
// counter + IDENTICAL deterministic double summation order -> bit-identical).
//
// Exactness (validated absmax 0.0 for this exact pipeline in r1-r3):
//  - img = (t>0.5)*255, integer Sobel => m multiple of 255 => weak==strong,
//    hysteresis fixed point => strong == cand.
//  - In 255-units: gx,gy in [-4,4], m <= 6 fits a nibble; SWAR compares
//    ((x|8)-y)&8 exact.
//  - horiz: ay==0&&ax>=1 || ay==1&&ax>=3 ; vert: ax==0&&ay>=1 || ay>=3&&ax==1
//  - bce = -max(log(t?p:1-p),-100); 1-p exact for p>=0.5 (Sterbenz).

typedef unsigned long long u64;
typedef unsigned int u32;
typedef unsigned short u16;

#define NT 256
#define H_IMG 1024
#define W_IMG 1024
#define WPR 32                 // packed u32 words per image row

constexpr u64 K1 = 0x1111111111111111ULL;
constexpr u64 K7 = 0x7777777777777777ULL;
constexpr u64 K8 = 0x8888888888888888ULL;

__device__ __forceinline__ u64 geq8(u64 x, u64 y) { return ((x | K8) - y) & K8; }
__device__ __forceinline__ u64 gt8(u64 x, u64 y) { return K8 & ~((y | K8) - x); }

// ---- pre-pass: binarize target to 1 bit/px ----
__global__ __launch_bounds__(256)
void binarize_kernel(const float* __restrict__ target, u32* __restrict__ packed,
                     int nwords)
{
    int t = blockIdx.x * 256 + threadIdx.x;
    if (t >= nwords) return;
    const float4* src = (const float4*)target + (size_t)t * 8;
    u32 v = 0;
#pragma unroll
    for (int k = 0; k < 8; ++k) {
        float4 f = src[k];
        v |= (f.x > 0.5f ? 1u : 0u) << (4 * k);
        v |= (f.y > 0.5f ? 2u : 0u) << (4 * k);
        v |= (f.z > 0.5f ? 4u : 0u) << (4 * k);
        v |= (f.w > 0.5f ? 8u : 0u) << (4 * k);
    }
    packed[t] = v;
}

__global__ __launch_bounds__(NT)
void edge_loss_kernel(const float* __restrict__ pred,
                      const u32* __restrict__ packed,
                      float* __restrict__ partials,
                      u32* __restrict__ done_ctr,
                      float* __restrict__ out,
                      int nblocks, double invN)
{
    __shared__ u32 simg[72][11];   // nibble-packed binarized target (q<=10)
    __shared__ u64 mw[70][6];      // m (nibbles, <=6); word5 zero
    __shared__ u64 clw[70][6];     // class nibbles: bit0=horiz bit1=vert bit2=sd
    __shared__ u16 ssw[68][5];     // strong, 16 px bitmasks
    __shared__ u64 hrow[68];       // horizontal 5-OR row masks
    __shared__ float wsum[NT / 64];
    __shared__ double dsum[NT / 64];
    __shared__ u32 lastf;

    const int tid = threadIdx.x;
    const int bz = blockIdx.z;
    const int r0 = blockIdx.y * 64;
    const int c0 = blockIdx.x * 64;
    const float* pimg = pred + (size_t)bz * H_IMG * W_IMG;
    const u32* pb = packed + (size_t)bz * H_IMG * WPR;
    const int W0 = c0 >> 5;        // even; c0 multiple of 64

    // ---- pred prefetch: 16 px/thread; loads stream during SWAR stages ----
    const int trow = tid >> 2;
    const int tcb = (tid & 3) * 16;
    const float4* pv4 = (const float4*)(pimg + (size_t)(r0 + trow) * W_IMG + (c0 + tcb));
    float4 pf[4];
#pragma unroll
    for (int k = 0; k < 4; ++k) pf[k] = pv4[k];

    // ---- Stage 0: packed bits -> nibble LDS, with edge-replicate clamp ----
    for (int t = tid; t < 72; t += NT) {
        int r = r0 - 4 + t; r = r < 0 ? 0 : (r > H_IMG - 1 ? H_IMG - 1 : r);
        const u32* prow = pb + r * WPR;
        u32 Bw = prow[W0];
        u32 Cw = prow[W0 + 1];
        u32 Aw = (W0 > 0) ? prow[W0 - 1] : ((Bw & 1u) ? ~0u : 0u);
        u32 Dw = (W0 + 2 < WPR) ? prow[W0 + 2] : ((Cw >> 31) ? ~0u : 0u);
        // 72-bit window, bit j = img col c0-4+j
        u64 lo = (u64)(Aw >> 28) | ((u64)Bw << 4) | ((u64)Cw << 36);
        u32 hi = (Cw >> 28) | ((Dw & 0xFu) << 4);
#pragma unroll
        for (int q = 0; q < 9; ++q) {
            u32 x = (q < 8) ? (u32)((lo >> (8 * q)) & 0xFFu) : (hi & 0xFFu);
            x = (x | (x << 12)) & 0x000F000Fu;   // spread 8 bits -> 8 nibbles
            x = (x | (x << 6))  & 0x03030303u;
            x = (x | (x << 3))  & 0x11111111u;
            simg[t][q] = x;
        }
        simg[t][9] = 0; simg[t][10] = 0;
    }
    __syncthreads();

    // ---- Stage A: SWAR Sobel -> m + class planes (16 px / task) ----
    for (int t = tid; t < 70 * 6; t += NT) {
        int mrow = t / 6, wi = t - mrow * 6;
        if (wi == 5) { mw[mrow][5] = 0; clw[mrow][5] = 0; continue; }
        u64 Lr[3], Cr[3], Rr[3];
#pragma unroll
        for (int k = 0; k < 3; ++k) {
            int ir = mrow + k;
            u32 a0 = simg[ir][2 * wi], a1 = simg[ir][2 * wi + 1], a2 = simg[ir][2 * wi + 2];
            u64 w0 = (u64)a0 | ((u64)a1 << 32);
            Lr[k] = w0;                                        // col-1
            Cr[k] = (w0 >> 4) | ((u64)(a2 & 0xFu) << 60);      // center
            Rr[k] = (w0 >> 8) | ((u64)(a2 & 0xFFu) << 56);     // col+1
        }
        u64 Px = Rr[0] + (Rr[1] << 1) + Rr[2];
        u64 Nx = Lr[0] + (Lr[1] << 1) + Lr[2];
        u64 Py = Lr[2] + (Cr[2] << 1) + Rr[2];
        u64 Ny = Lr[0] + (Cr[0] << 1) + Rr[0];
        u64 Dbx = (Px + K8) - Nx;                // gx+8 per nibble, no borrows
        u64 Dby = (Py + K8) - Ny;

        u64 mx = (Dbx >> 3) & K1;                // gx >= 0
        u64 mfx = (mx << 4) - mx;
        u64 ax = ((Dbx & K7) & mfx) | (((((~Dbx) & K7) + K1)) & ~mfx);
        u64 my = (Dby >> 3) & K1;
        u64 mfy = (my << 4) - my;
        u64 ay = ((Dby & K7) & mfy) | (((((~Dby) & K7) + K1)) & ~mfy);
        u64 m = ax + ay;                         // <= 6

        u64 ax0 = ax & K1, ax1b = (ax >> 1) & K1, ax2b = (ax >> 2) & K1;
        u64 ay0 = ay & K1, ay1b = (ay >> 1) & K1, ay2b = (ay >> 2) & K1;
        u64 axnz = ax0 | ax1b | ax2b;
        u64 aynz = ay0 | ay1b | ay2b;
        u64 axe1 = ax0 & ~(ax1b | ax2b);
        u64 aye1 = ay0 & ~(ay1b | ay2b);
        u64 axg3 = ax2b | (ax1b & ax0);
        u64 ayg3 = ay2b | (ay1b & ay0);
        u64 horiz = ((K1 & ~aynz) & axnz) | (aye1 & axg3);
        u64 vert  = ((K1 & ~axnz) & aynz) | (axe1 & ayg3);

        u64 gxp = mx & ((Dbx | (Dbx >> 1) | (Dbx >> 2)) & K1);
        u64 gxn = K1 & ~mx;
        u64 gyp = my & ((Dby | (Dby >> 1) | (Dby >> 2)) & K1);
        u64 gyn = K1 & ~my;
        u64 sd = (gxp & gyn) | (gxn & gyp);

        mw[mrow][wi] = m;
        clw[mrow][wi] = horiz | (vert << 1) | (sd << 2);
    }
    __syncthreads();

    // ---- Stage B: SWAR NMS + threshold + interior -> strong bitmasks ----
    for (int t = tid; t < 68 * 5; t += NT) {
        int srow = t / 5, wi = t - srow * 5;
        u16 outm = 0;
        int rr = r0 - 2 + srow;
        if (rr >= 1 && rr <= H_IMG - 2) {
            int ra = srow, rb = srow + 1, rc = srow + 2;
            u64 a0 = mw[ra][wi], a1 = mw[ra][wi + 1];
            u64 b0 = mw[rb][wi], b1 = mw[rb][wi + 1];
            u64 g0 = mw[rc][wi], g1 = mw[rc][wi + 1];
            u64 U  = (a0 >> 4) | (a1 << 60);
            u64 UL = a0;
            u64 UR = (a0 >> 8) | (a1 << 56);
            u64 M  = (b0 >> 4) | (b1 << 60);
            u64 Lf = b0;
            u64 Rg = (b0 >> 8) | (b1 << 56);
            u64 Dn = (g0 >> 4) | (g1 << 60);
            u64 DL = g0;
            u64 DR = (g0 >> 8) | (g1 << 56);

            u64 q0 = clw[rb][wi], q1 = clw[rb][wi + 1];
            u64 CC = (q0 >> 4) | (q1 << 60);
            u64 H8 = (CC & K1) << 3;
            u64 V8 = ((CC >> 1) & K1) << 3;
            u64 S8 = ((CC >> 2) & K1) << 3;

            u64 kH = gt8(M, Lf) & geq8(M, Rg);
            u64 kV = gt8(M, U)  & geq8(M, Dn);
            u64 kA = gt8(M, UR) & geq8(M, DL);
            u64 kB = gt8(M, UL) & geq8(M, DR);
            u64 nHV = K8 & ~(H8 | V8);
            u64 keep = (H8 & kH) | (V8 & kV) | (nHV & S8 & kA) | (nHV & ~S8 & kB);
            u64 nz = ((M | (M >> 1) | (M >> 2)) & K1) << 3;   // m >= 1
            u64 cand = keep & nz;

            int basec = c0 - 2 + 16 * wi;
            int lo = 1 - basec; if (lo < 0) lo = 0;
            int hi = (W_IMG - 2) - basec; if (hi > 15) hi = 15;
            if (lo > hi) cand = 0;
            else cand &= (~0ULL >> ((15 - hi) * 4)) & (~0ULL << (lo * 4));

            u64 x = cand >> 3;
            x = (x | (x >> 3))  & 0x0303030303030303ULL;
            x = (x | (x >> 6))  & 0x000F000F000F000FULL;
            x = (x | (x >> 12)) & 0x000000FF000000FFULL;
            x = (x | (x >> 24));
            outm = (u16)(x & 0xFFFF);
        }
        ssw[srow][wi] = outm;
    }
    __syncthreads();

    // ---- Stage C: horizontal 5-OR over strong row bitmasks ----
    for (int t = tid; t < 68; t += NT) {
        u64 lo = (u64)ssw[t][0] | ((u64)ssw[t][1] << 16) |
                 ((u64)ssw[t][2] << 32) | ((u64)ssw[t][3] << 48);
        u64 hib = (u64)(ssw[t][4] & 0xFu);
        u64 acc = lo;
#pragma unroll
        for (int d = 1; d <= 4; ++d)
            acc |= (lo >> d) | (hib << (64 - d));
        hrow[t] = acc;
    }
    __syncthreads();

    // ---- Stage D: vertical 5-OR + weighted BCE; 16 px / thread ----
    float accv = 0.0f;
    {
        u64 ez64 = hrow[trow] | hrow[trow + 1] | hrow[trow + 2] |
                   hrow[trow + 3] | hrow[trow + 4];
        u64 ezw = ez64 >> tcb;
        int q = (tcb + 4) >> 3;
        u32 ua = simg[trow + 4][q], ub = simg[trow + 4][q + 1], uc = simg[trow + 4][q + 2];
        u64 tb = ((u64)(ua >> 16)) | ((u64)ub << 16) | (((u64)(uc & 0xFFFFu)) << 48);
#pragma unroll
        for (int kk = 0; kk < 4; ++kk) {
            float4 pv = pf[kk];
            float ps[4] = {pv.x, pv.y, pv.z, pv.w};
#pragma unroll
            for (int cc = 0; cc < 4; ++cc) {
                int k = kk * 4 + cc;
                float p = ps[cc];
                float xx = ((tb >> (4 * k)) & 1) ? p : 1.0f - p;
                float lg = fmaxf(__logf(xx), -100.0f);
                float w = ((ezw >> k) & 1) ? 5.0f : 1.0f;
                accv = fmaf(w, -lg, accv);
            }
        }
    }

    for (int off = 32; off > 0; off >>= 1)
        accv += __shfl_down(accv, off);
    int wid = tid >> 6, lane = tid & 63;
    if (lane == 0) wsum[wid] = accv;
    __syncthreads();
    if (tid == 0) {
        int bi = (blockIdx.z * gridDim.y + blockIdx.y) * gridDim.x + blockIdx.x;
        partials[bi] = wsum[0] + wsum[1] + wsum[2] + wsum[3];
        __threadfence();
        u32 r = atomicAdd(done_ctr, 1u);
        lastf = (r == (u32)(nblocks - 1)) ? 1u : 0u;
    }
    __syncthreads();

    // ---- last block: final reduction (exact finalize-kernel order) ----
    if (lastf) {
        __threadfence();
        double s = 0.0;
        for (int i = tid; i < nblocks; i += NT)
            s += (double)((volatile float*)partials)[i];
        for (int off = 32; off > 0; off >>= 1)
            s += __shfl_down(s, off);
        if (lane == 0) dsum[wid] = s;
        __syncthreads();
        if (tid == 0) {
            out[0] = (float)((dsum[0] + dsum[1] + dsum[2] + dsum[3]) * invN);
            *done_ctr = 0;                    // self-reset for next launch
        }
    }
}

extern "C" void kernel_launch(void* const* d_in, const int* in_sizes, int n_in,
                              void* d_out, int out_size, void* d_ws, size_t ws_size,
                              hipStream_t stream)
{
    (void)n_in; (void)out_size; (void)ws_size;
    const float* pred   = (const float*)d_in[0];
    const float* target = (const float*)d_in[1];
    const int N = in_sizes[0];
    const int B = N / (H_IMG * W_IMG);

    // ws layout: [0,16KB) per-block partials; [16KB,16KB+2MB) packed bits;
    // [16KB+2MB] done counter
    float* partials = (float*)d_ws;
    u32* packed = (u32*)((char*)d_ws + 16384);
    u32* done_ctr = (u32*)((char*)d_ws + 16384 + (size_t)2 * 1024 * 1024);
    const int nwords = B * H_IMG * WPR;          // 524288 (2 MB)

    hipMemsetAsync(done_ctr, 0, 4, stream);

    binarize_kernel<<<(nwords + 255) / 256, 256, 0, stream>>>(target, packed, nwords);

    dim3 grid(W_IMG / 64, H_IMG / 64, B);
    int nblocks = (W_IMG / 64) * (H_IMG / 64) * B;
    edge_loss_kernel<<<grid, NT, 0, stream>>>(pred, packed, partials, done_ctr,
                                              (float*)d_out, nblocks,
                                              1.0 / (double)N);
}

// Round 8
// 44.785 us; speedup vs baseline: 2.9254x; 2.9254x over previous
//
#include <hip/hip_runtime.h>
#include <math.h>

// EdgeAwareLoss — round 11: champion restore (r3 structure, byte-for-byte).
//
// Session ledger: this 3-kernel nibble-SWAR pipeline measured 44.8us (r3 /
// round-0 baseline). Structural variants all regressed: fused binarize 48.5,
// bit-sliced 45.8, stream/stencil 4-kernel split 49.2, 32-row bands 45.3,
// 16-row bands 64.3, wave-autonomous 67.5, last-block-fence fold 131.0
// (threadfence per block = cross-XCD L2 drain; never again at high block
// counts). Locking in the session best.
//
// Exactness arguments vs the JAX reference (validated absmax 0.0 repeatedly):
//  - img = (t>0.5)*255, integer Sobel => m is a multiple of 255, so
//    (m>50)==(m>150): weak==strong, hysteresis loop is an immediate fixed
//    point => strong == cand. No iteration.
//  - In units of 255: gx,gy in [-4,4], |gx|+|gy| <= 6, so m fits a nibble and
//    SWAR compares ((x|8)-y)&8 are exact (values <= 7).
//  - Direction classes enumerated exactly over the integer grid:
//      horiz (ay < ax*tan22.5): ay==0&&ax>=1 || ay==1&&ax>=3
//      vert  (ay > ax*tan67.5): ax==0&&ay>=1 || ax==1&&ay>=3
//  - t in {0,1} => bce = -max(log(t?p:1-p), -100); 1-p exact for p>=0.5
//    (Sterbenz) and >=0.5 otherwise.

typedef unsigned long long u64;
typedef unsigned int u32;
typedef unsigned short u16;

#define NT 256
#define H_IMG 1024
#define W_IMG 1024
#define WPR 32                 // packed u32 words per image row

constexpr u64 K1 = 0x1111111111111111ULL;
constexpr u64 K7 = 0x7777777777777777ULL;
constexpr u64 K8 = 0x8888888888888888ULL;

__device__ __forceinline__ u64 geq8(u64 x, u64 y) { return ((x | K8) - y) & K8; }
__device__ __forceinline__ u64 gt8(u64 x, u64 y) { return K8 & ~((y | K8) - x); }

// ---- pre-pass: binarize target to 1 bit/px ----
__global__ __launch_bounds__(256)
void binarize_kernel(const float* __restrict__ target, u32* __restrict__ packed,
                     int nwords)
{
    int t = blockIdx.x * 256 + threadIdx.x;
    if (t >= nwords) return;
    const float4* src = (const float4*)target + (size_t)t * 8;
    u32 v = 0;
#pragma unroll
    for (int k = 0; k < 8; ++k) {
        float4 f = src[k];
        v |= (f.x > 0.5f ? 1u : 0u) << (4 * k);
        v |= (f.y > 0.5f ? 2u : 0u) << (4 * k);
        v |= (f.z > 0.5f ? 4u : 0u) << (4 * k);
        v |= (f.w > 0.5f ? 8u : 0u) << (4 * k);
    }
    packed[t] = v;
}

__global__ __launch_bounds__(NT)
void edge_loss_kernel(const float* __restrict__ pred,
                      const u32* __restrict__ packed,
                      float* __restrict__ partials)
{
    __shared__ u32 simg[72][11];   // nibble-packed binarized target (q<=10)
    __shared__ u64 mw[70][6];      // m (nibbles, <=6); word5 zero
    __shared__ u64 clw[70][6];     // class nibbles: bit0=horiz bit1=vert bit2=sd
    __shared__ u16 ssw[68][5];     // strong, 16 px bitmasks
    __shared__ u64 hrow[68];       // horizontal 5-OR row masks
    __shared__ float wsum[NT / 64];

    const int tid = threadIdx.x;
    const int bz = blockIdx.z;
    const int r0 = blockIdx.y * 64;
    const int c0 = blockIdx.x * 64;
    const float* pimg = pred + (size_t)bz * H_IMG * W_IMG;
    const u32* pb = packed + (size_t)bz * H_IMG * WPR;
    const int W0 = c0 >> 5;        // even; c0 multiple of 64

    // ---- Stage 0: packed bits -> nibble LDS, with edge-replicate clamp ----
    for (int t = tid; t < 72; t += NT) {
        int r = r0 - 4 + t; r = r < 0 ? 0 : (r > H_IMG - 1 ? H_IMG - 1 : r);
        const u32* prow = pb + r * WPR;
        u32 Bw = prow[W0];
        u32 Cw = prow[W0 + 1];
        u32 Aw = (W0 > 0) ? prow[W0 - 1] : ((Bw & 1u) ? ~0u : 0u);
        u32 Dw = (W0 + 2 < WPR) ? prow[W0 + 2] : ((Cw >> 31) ? ~0u : 0u);
        // 72-bit window, bit j = img col c0-4+j
        u64 lo = (u64)(Aw >> 28) | ((u64)Bw << 4) | ((u64)Cw << 36);
        u32 hi = (Cw >> 28) | ((Dw & 0xFu) << 4);
#pragma unroll
        for (int q = 0; q < 9; ++q) {
            u32 x = (q < 8) ? (u32)((lo >> (8 * q)) & 0xFFu) : (hi & 0xFFu);
            x = (x | (x << 12)) & 0x000F000Fu;   // spread 8 bits -> 8 nibbles
            x = (x | (x << 6))  & 0x03030303u;
            x = (x | (x << 3))  & 0x11111111u;
            simg[t][q] = x;
        }
        simg[t][9] = 0; simg[t][10] = 0;
    }
    __syncthreads();

    // ---- Stage A: SWAR Sobel -> m + class planes (16 px / task) ----
    for (int t = tid; t < 70 * 6; t += NT) {
        int mrow = t / 6, wi = t - mrow * 6;
        if (wi == 5) { mw[mrow][5] = 0; clw[mrow][5] = 0; continue; }
        u64 Lr[3], Cr[3], Rr[3];
#pragma unroll
        for (int k = 0; k < 3; ++k) {
            int ir = mrow + k;
            u32 a0 = simg[ir][2 * wi], a1 = simg[ir][2 * wi + 1], a2 = simg[ir][2 * wi + 2];
            u64 w0 = (u64)a0 | ((u64)a1 << 32);
            Lr[k] = w0;                                        // col-1
            Cr[k] = (w0 >> 4) | ((u64)(a2 & 0xFu) << 60);      // center
            Rr[k] = (w0 >> 8) | ((u64)(a2 & 0xFFu) << 56);     // col+1
        }
        u64 Px = Rr[0] + (Rr[1] << 1) + Rr[2];
        u64 Nx = Lr[0] + (Lr[1] << 1) + Lr[2];
        u64 Py = Lr[2] + (Cr[2] << 1) + Rr[2];
        u64 Ny = Lr[0] + (Cr[0] << 1) + Rr[0];
        u64 Dbx = (Px + K8) - Nx;                // gx+8 per nibble, no borrows
        u64 Dby = (Py + K8) - Ny;

        u64 mx = (Dbx >> 3) & K1;                // gx >= 0
        u64 mfx = (mx << 4) - mx;
        u64 ax = ((Dbx & K7) & mfx) | (((((~Dbx) & K7) + K1)) & ~mfx);
        u64 my = (Dby >> 3) & K1;
        u64 mfy = (my << 4) - my;
        u64 ay = ((Dby & K7) & mfy) | (((((~Dby) & K7) + K1)) & ~mfy);
        u64 m = ax + ay;                         // <= 6

        u64 ax0 = ax & K1, ax1b = (ax >> 1) & K1, ax2b = (ax >> 2) & K1;
        u64 ay0 = ay & K1, ay1b = (ay >> 1) & K1, ay2b = (ay >> 2) & K1;
        u64 axnz = ax0 | ax1b | ax2b;
        u64 aynz = ay0 | ay1b | ay2b;
        u64 axe1 = ax0 & ~(ax1b | ax2b);
        u64 aye1 = ay0 & ~(ay1b | ay2b);
        u64 axg3 = ax2b | (ax1b & ax0);
        u64 ayg3 = ay2b | (ay1b & ay0);
        u64 horiz = ((K1 & ~aynz) & axnz) | (aye1 & axg3);
        u64 vert  = ((K1 & ~axnz) & aynz) | (axe1 & ayg3);

        u64 gxp = mx & ((Dbx | (Dbx >> 1) | (Dbx >> 2)) & K1);
        u64 gxn = K1 & ~mx;
        u64 gyp = my & ((Dby | (Dby >> 1) | (Dby >> 2)) & K1);
        u64 gyn = K1 & ~my;
        u64 sd = (gxp & gyn) | (gxn & gyp);

        mw[mrow][wi] = m;
        clw[mrow][wi] = horiz | (vert << 1) | (sd << 2);
    }
    __syncthreads();

    // ---- Stage B: SWAR NMS + threshold + interior -> strong bitmasks ----
    for (int t = tid; t < 68 * 5; t += NT) {
        int srow = t / 5, wi = t - srow * 5;
        u16 outm = 0;
        int rr = r0 - 2 + srow;
        if (rr >= 1 && rr <= H_IMG - 2) {
            int ra = srow, rb = srow + 1, rc = srow + 2;
            u64 a0 = mw[ra][wi], a1 = mw[ra][wi + 1];
            u64 b0 = mw[rb][wi], b1 = mw[rb][wi + 1];
            u64 g0 = mw[rc][wi], g1 = mw[rc][wi + 1];
            u64 U  = (a0 >> 4) | (a1 << 60);
            u64 UL = a0;
            u64 UR = (a0 >> 8) | (a1 << 56);
            u64 M  = (b0 >> 4) | (b1 << 60);
            u64 Lf = b0;
            u64 Rg = (b0 >> 8) | (b1 << 56);
            u64 Dn = (g0 >> 4) | (g1 << 60);
            u64 DL = g0;
            u64 DR = (g0 >> 8) | (g1 << 56);

            u64 q0 = clw[rb][wi], q1 = clw[rb][wi + 1];
            u64 CC = (q0 >> 4) | (q1 << 60);
            u64 H8 = (CC & K1) << 3;
            u64 V8 = ((CC >> 1) & K1) << 3;
            u64 S8 = ((CC >> 2) & K1) << 3;

            u64 kH = gt8(M, Lf) & geq8(M, Rg);
            u64 kV = gt8(M, U)  & geq8(M, Dn);
            u64 kA = gt8(M, UR) & geq8(M, DL);
            u64 kB = gt8(M, UL) & geq8(M, DR);
            u64 nHV = K8 & ~(H8 | V8);
            u64 keep = (H8 & kH) | (V8 & kV) | (nHV & S8 & kA) | (nHV & ~S8 & kB);
            u64 nz = ((M | (M >> 1) | (M >> 2)) & K1) << 3;   // m >= 1
            u64 cand = keep & nz;

            int basec = c0 - 2 + 16 * wi;
            int lo = 1 - basec; if (lo < 0) lo = 0;
            int hi = (W_IMG - 2) - basec; if (hi > 15) hi = 15;
            if (lo > hi) cand = 0;
            else cand &= (~0ULL >> ((15 - hi) * 4)) & (~0ULL << (lo * 4));

            u64 x = cand >> 3;
            x = (x | (x >> 3))  & 0x0303030303030303ULL;
            x = (x | (x >> 6))  & 0x000F000F000F000FULL;
            x = (x | (x >> 12)) & 0x000000FF000000FFULL;
            x = (x | (x >> 24));
            outm = (u16)(x & 0xFFFF);
        }
        ssw[srow][wi] = outm;
    }
    __syncthreads();

    // ---- Stage C: horizontal 5-OR over strong row bitmasks ----
    for (int t = tid; t < 68; t += NT) {
        u64 lo = (u64)ssw[t][0] | ((u64)ssw[t][1] << 16) |
                 ((u64)ssw[t][2] << 32) | ((u64)ssw[t][3] << 48);
        u64 hib = (u64)(ssw[t][4] & 0xFu);
        u64 acc = lo;
#pragma unroll
        for (int d = 1; d <= 4; ++d)
            acc |= (lo >> d) | (hib << (64 - d));
        hrow[t] = acc;
    }
    __syncthreads();

    // ---- Stage D: vertical 5-OR + weighted BCE; 16 px / thread ----
    float accv = 0.0f;
    {
        int trow = tid >> 2;
        int tcb = (tid & 3) * 16;
        u64 ez64 = hrow[trow] | hrow[trow + 1] | hrow[trow + 2] |
                   hrow[trow + 3] | hrow[trow + 4];
        u64 ezw = ez64 >> tcb;
        int q = (tcb + 4) >> 3;
        u32 ua = simg[trow + 4][q], ub = simg[trow + 4][q + 1], uc = simg[trow + 4][q + 2];
        u64 tb = ((u64)(ua >> 16)) | ((u64)ub << 16) | (((u64)(uc & 0xFFFFu)) << 48);
        const float4* pv4 = (const float4*)(pimg + (size_t)(r0 + trow) * W_IMG + (c0 + tcb));
#pragma unroll
        for (int kk = 0; kk < 4; ++kk) {
            float4 pv = pv4[kk];
            float ps[4] = {pv.x, pv.y, pv.z, pv.w};
#pragma unroll
            for (int cc = 0; cc < 4; ++cc) {
                int k = kk * 4 + cc;
                float p = ps[cc];
                float xx = ((tb >> (4 * k)) & 1) ? p : 1.0f - p;
                float lg = fmaxf(__logf(xx), -100.0f);
                float w = ((ezw >> k) & 1) ? 5.0f : 1.0f;
                accv = fmaf(w, -lg, accv);
            }
        }
    }

    for (int off = 32; off > 0; off >>= 1)
        accv += __shfl_down(accv, off);
    int wid = tid >> 6, lane = tid & 63;
    if (lane == 0) wsum[wid] = accv;
    __syncthreads();
    if (tid == 0) {
        int bi = (blockIdx.z * gridDim.y + blockIdx.y) * gridDim.x + blockIdx.x;
        partials[bi] = wsum[0] + wsum[1] + wsum[2] + wsum[3];
    }
}

__global__ __launch_bounds__(256)
void finalize_kernel(const float* __restrict__ partials, float* __restrict__ out,
                     int nblocks, double invN)
{
    __shared__ double ws[4];
    double s = 0.0;
    for (int i = threadIdx.x; i < nblocks; i += 256) s += (double)partials[i];
    for (int off = 32; off > 0; off >>= 1) s += __shfl_down(s, off);
    int wid = threadIdx.x >> 6, lane = threadIdx.x & 63;
    if (lane == 0) ws[wid] = s;
    __syncthreads();
    if (threadIdx.x == 0) out[0] = (float)((ws[0] + ws[1] + ws[2] + ws[3]) * invN);
}

extern "C" void kernel_launch(void* const* d_in, const int* in_sizes, int n_in,
                              void* d_out, int out_size, void* d_ws, size_t ws_size,
                              hipStream_t stream)
{
    (void)n_in; (void)out_size; (void)ws_size;
    const float* pred   = (const float*)d_in[0];
    const float* target = (const float*)d_in[1];
    const int N = in_sizes[0];
    const int B = N / (H_IMG * W_IMG);

    // ws layout: [0,16KB) per-block partials; [16KB, 16KB+2MB) packed target bits
    float* partials = (float*)d_ws;
    u32* packed = (u32*)((char*)d_ws + 16384);
    const int nwords = B * H_IMG * WPR;          // 524288 (2 MB)

    binarize_kernel<<<(nwords + 255) / 256, 256, 0, stream>>>(target, packed, nwords);

    dim3 grid(W_IMG / 64, H_IMG / 64, B);
    int nblocks = (W_IMG / 64) * (H_IMG / 64) * B;
    edge_loss_kernel<<<grid, NT, 0, stream>>>(pred, packed, partials);
    finalize_kernel<<<1, 256, 0, stream>>>(partials, (float*)d_out, nblocks,
                                           1.0 / (double)N);
}